// Round 1
// baseline (1314.324 us; speedup 1.0000x reference)
//
#include <hip/hip_runtime.h>
#include <math.h>

#define NBATCH 2
#define CHN 128
#define HIMG 128
#define WIMG 128
#define DDIM 64
#define NP 4096   // 64*64 downsampled positions

// ---------------- downsample x: xf[nb][ch][m] ----------------
__global__ __launch_bounds__(256) void k_down_x(const float* __restrict__ x,
                                                const float* __restrict__ dw,
                                                float* __restrict__ xf) {
  int idx = blockIdx.x * 256 + threadIdx.x;      // exactly NBATCH*CHN*NP threads
  int m  = idx & (NP - 1);
  int ch = (idx >> 12) & (CHN - 1);
  int nb = idx >> 19;
  int i = m >> 6, j = m & 63;
  const float* xb = x + (((size_t)nb * CHN + ch) * HIMG + 2 * i) * WIMG + 2 * j;
  const float* w = dw + ch * 4;
  xf[idx] = xb[0] * w[0] + xb[1] * w[1] + xb[WIMG] * w[2] + xb[WIMG + 1] * w[3];
}

// ---------------- downsample depth: df[nb][m] ----------------
__global__ __launch_bounds__(256) void k_down_d(const float* __restrict__ dmap,
                                                const float* __restrict__ ddw,
                                                float* __restrict__ df) {
  int idx = blockIdx.x * 256 + threadIdx.x;      // exactly NBATCH*NP threads
  int m = idx & (NP - 1);
  int nb = idx >> 12;
  int i = m >> 6, j = m & 63;
  const float* xb = dmap + ((size_t)nb * HIMG + 2 * i) * WIMG + 2 * j;
  df[idx] = xb[0] * ddw[0] + xb[1] * ddw[1] + xb[WIMG] * ddw[2] + xb[WIMG + 1] * ddw[3];
}

// ---------------- 1x1 conv: out = W(64x128) @ xf + b ----------------
// layout 0: out[nb][k][m]   layout 1: out[nb][m][k]
__global__ __launch_bounds__(256) void k_conv1x1(const float* __restrict__ xf,
                                                 const float* __restrict__ W,
                                                 const float* __restrict__ bias,
                                                 float* __restrict__ out, int layout) {
  __shared__ __align__(16) float xs[CHN][64];    // 32KB
  int nb = blockIdx.y;
  int m0 = blockIdx.x * 64;
  int t = threadIdx.x;
  const float* xb = xf + (size_t)nb * CHN * NP + m0;
  for (int e = t; e < CHN * 64; e += 256) {
    int c = e >> 6, mm = e & 63;
    xs[c][mm] = xb[(size_t)c * NP + mm];
  }
  __syncthreads();
  int tm = t & 15;   // m' = tm*4 + [0..3]
  int tk = t >> 4;   // k  = tk*4 + [0..3]
  float acc[4][4] = {};
  for (int c = 0; c < CHN; ++c) {
    float w0 = W[(tk * 4 + 0) * CHN + c];
    float w1 = W[(tk * 4 + 1) * CHN + c];
    float w2 = W[(tk * 4 + 2) * CHN + c];
    float w3 = W[(tk * 4 + 3) * CHN + c];
    float4 xv = *(const float4*)&xs[c][tm * 4];
    acc[0][0] += w0 * xv.x; acc[0][1] += w0 * xv.y; acc[0][2] += w0 * xv.z; acc[0][3] += w0 * xv.w;
    acc[1][0] += w1 * xv.x; acc[1][1] += w1 * xv.y; acc[1][2] += w1 * xv.z; acc[1][3] += w1 * xv.w;
    acc[2][0] += w2 * xv.x; acc[2][1] += w2 * xv.y; acc[2][2] += w2 * xv.z; acc[2][3] += w2 * xv.w;
    acc[3][0] += w3 * xv.x; acc[3][1] += w3 * xv.y; acc[3][2] += w3 * xv.z; acc[3][3] += w3 * xv.w;
  }
  if (layout == 0) {
    for (int i = 0; i < 4; ++i) {
      float b = bias[tk * 4 + i];
      float4 st = { acc[i][0] + b, acc[i][1] + b, acc[i][2] + b, acc[i][3] + b };
      *(float4*)&out[((size_t)nb * DDIM + tk * 4 + i) * NP + m0 + tm * 4] = st;
    }
  } else {
    for (int i = 0; i < 4; ++i) {
      float b = bias[tk * 4 + i];
      for (int j = 0; j < 4; ++j)
        out[((size_t)nb * NP + m0 + tm * 4 + j) * DDIM + tk * 4 + i] = acc[i][j] + b;
    }
  }
}

// ---------------- u,v from phi (rank-2 Ra logits precompute) ----------------
__global__ __launch_bounds__(256) void k_uv(const float* __restrict__ phi,
                                            const float* __restrict__ tw,
                                            const float* __restrict__ tb,
                                            float* __restrict__ u, float* __restrict__ v) {
  int idx = blockIdx.x * 256 + threadIdx.x;  // NBATCH*NP
  int m = idx & (NP - 1);
  int nb = idx >> 12;
  const float* pb = phi + (size_t)nb * DDIM * NP + m;
  float uu = 0.f, vv = 0.f;
  for (int k = 0; k < DDIM; ++k) {
    float ph = pb[(size_t)k * NP];
    uu += tw[k] * ph;
    vv += tb[k] * ph;
  }
  u[idx] = uu; v[idx] = vv;
}

// ---------------- fused triple flash attention ----------------
// fused[nb][l][k] = Ra@g1 + Rb@g2 + Rc@g3 (each row-softmax-normalized online)
__global__ __launch_bounds__(256) void k_attn(
    const float* __restrict__ fphi, const float* __restrict__ ftheta,
    const float* __restrict__ g1, const float* __restrict__ g2, const float* __restrict__ g3,
    const float* __restrict__ df, const float* __restrict__ u, const float* __restrict__ v,
    const float* __restrict__ dtw, const float* __restrict__ dtb, const float* __restrict__ dpw,
    float* __restrict__ fused) {
  __shared__ __align__(16) float qs[32][68];     // padded: avoids 8-way on q broadcast
  __shared__ __align__(16) float Ks[64][64];     // Ks[k][m']
  __shared__ __align__(16) float Vs[64][64];     // Vs[m'][k] (reused g1->g2->g3)
  __shared__ __align__(16) float ps[64][36];     // ps[m'][r], stride 36: f4-aligned rows
  __shared__ __align__(16) float us[64], vs[64], dfm[64];
  __shared__ float scale_s[3][32];
  __shared__ float dfin_s[3][32];

  int t = threadIdx.x;
  int nb = blockIdx.y;
  int l0 = blockIdx.x * 32;
  const size_t base  = (size_t)nb * NP;
  const size_t base2 = (size_t)nb * DDIM * NP;
  const float* g1p = g1 + base * DDIM;
  const float* g2p = g2 + base * DDIM;
  const float* g3p = g3 + base * DDIM;
  const float* dfp = df + base;
  const float* up  = u + base;
  const float* vp  = v + base;

  // persistent Q tile
  const float* qb = ftheta + (base + l0) * DDIM;
  for (int e = t; e < 32 * DDIM; e += 256) { int r = e >> 6, k = e & 63; qs[r][k] = qb[e]; }

  // logit-phase mapping: 1 row x 8 m's
  int lr = t >> 3, lm = t & 7;
  float df_l = dfp[l0 + lr];
  float A = 0.f, Cc = 0.f;
  for (int k = 0; k < DDIM; ++k) { A += dtw[k] * dpw[k]; Cc += dtb[k] * dpw[k]; }
  float s_l = A * df_l + Cc;
  float m_a = -1e30f, m_b = -1e30f, m_c = -1e30f;
  float d_a = 0.f, d_b = 0.f, d_c = 0.f;

  // pv-phase mapping: 4 rows x 2 k's
  int tr = t >> 5, tk = t & 31;
  float acc_a[4][2] = {}, acc_b[4][2] = {}, acc_c[4][2] = {};

  auto softmax_update = [&](float* S, float& mr, float& dr, int MAT) {
    float tmax = S[0];
#pragma unroll
    for (int j = 1; j < 8; ++j) tmax = fmaxf(tmax, S[j]);
    tmax = fmaxf(tmax, __shfl_xor(tmax, 1));
    tmax = fmaxf(tmax, __shfl_xor(tmax, 2));
    tmax = fmaxf(tmax, __shfl_xor(tmax, 4));
    float mn = fmaxf(mr, tmax);
    float sc = __expf(mr - mn);
    float p[8]; float psum = 0.f;
#pragma unroll
    for (int j = 0; j < 8; ++j) { p[j] = __expf(S[j] - mn); psum += p[j]; }
    psum += __shfl_xor(psum, 1);
    psum += __shfl_xor(psum, 2);
    psum += __shfl_xor(psum, 4);
    dr = dr * sc + psum; mr = mn;
    if (lm == 0) scale_s[MAT][lr] = sc;
#pragma unroll
    for (int j = 0; j < 8; ++j) ps[lm * 8 + j][lr] = p[j];
  };

  auto pv_acc = [&](float (&acc)[4][2], int MAT) {
    float s0 = scale_s[MAT][tr * 4 + 0];
    float s1 = scale_s[MAT][tr * 4 + 1];
    float s2 = scale_s[MAT][tr * 4 + 2];
    float s3 = scale_s[MAT][tr * 4 + 3];
    acc[0][0] *= s0; acc[0][1] *= s0;
    acc[1][0] *= s1; acc[1][1] *= s1;
    acc[2][0] *= s2; acc[2][1] *= s2;
    acc[3][0] *= s3; acc[3][1] *= s3;
#pragma unroll 8
    for (int mm = 0; mm < 64; ++mm) {
      float4 pvv = *(const float4*)&ps[mm][tr * 4];
      float2 vv  = *(const float2*)&Vs[mm][tk * 2];
      acc[0][0] += pvv.x * vv.x; acc[0][1] += pvv.x * vv.y;
      acc[1][0] += pvv.y * vv.x; acc[1][1] += pvv.y * vv.y;
      acc[2][0] += pvv.z * vv.x; acc[2][1] += pvv.z * vv.y;
      acc[3][0] += pvv.w * vv.x; acc[3][1] += pvv.w * vv.y;
    }
  };

  for (int m0 = 0; m0 < NP; m0 += 64) {
    __syncthreads();   // prev tile fully done with Ks/Vs/ps
    for (int e = t; e < 4096; e += 256) {
      int k = e >> 6, mm = e & 63;
      Ks[k][mm] = fphi[base2 + (size_t)k * NP + m0 + mm];
    }
    for (int e = t; e < 4096; e += 256) {
      int mm = e >> 6, k = e & 63;
      Vs[mm][k] = g1p[(size_t)(m0 + mm) * DDIM + k];
    }
    if (t < 64) dfm[t] = dfp[m0 + t];
    else if (t < 128) us[t - 64] = up[m0 + t - 64];
    else if (t < 192) vs[t - 128] = vp[m0 + t - 128];
    __syncthreads();

    // ---- logits (logit mapping) ----
    float Sc[8] = {0,0,0,0,0,0,0,0};
#pragma unroll 8
    for (int k = 0; k < 64; ++k) {
      float q = qs[lr][k];
      const float4* Kr = (const float4*)&Ks[k][0];
      float4 a0 = Kr[lm * 2], a1 = Kr[lm * 2 + 1];
      Sc[0] += q * a0.x; Sc[1] += q * a0.y; Sc[2] += q * a0.z; Sc[3] += q * a0.w;
      Sc[4] += q * a1.x; Sc[5] += q * a1.y; Sc[6] += q * a1.z; Sc[7] += q * a1.w;
    }
    float Sa[8], Sb[8];
    {
      const float4* u4 = (const float4*)us;
      const float4* v4 = (const float4*)vs;
      const float4* d4 = (const float4*)dfm;
      float4 uu0 = u4[lm * 2], uu1 = u4[lm * 2 + 1];
      float4 vv0 = v4[lm * 2], vv1 = v4[lm * 2 + 1];
      float4 dd0 = d4[lm * 2], dd1 = d4[lm * 2 + 1];
      Sa[0] = df_l * uu0.x + vv0.x; Sa[1] = df_l * uu0.y + vv0.y;
      Sa[2] = df_l * uu0.z + vv0.z; Sa[3] = df_l * uu0.w + vv0.w;
      Sa[4] = df_l * uu1.x + vv1.x; Sa[5] = df_l * uu1.y + vv1.y;
      Sa[6] = df_l * uu1.z + vv1.z; Sa[7] = df_l * uu1.w + vv1.w;
      Sb[0] = s_l * dd0.x; Sb[1] = s_l * dd0.y; Sb[2] = s_l * dd0.z; Sb[3] = s_l * dd0.w;
      Sb[4] = s_l * dd1.x; Sb[5] = s_l * dd1.y; Sb[6] = s_l * dd1.z; Sb[7] = s_l * dd1.w;
    }

    // ---- A: p_a with V=g1 (already staged) ----
    softmax_update(Sa, m_a, d_a, 0);
    __syncthreads();
    pv_acc(acc_a, 0);
    __syncthreads();
    // ---- B: restage V=g2 ----
    for (int e = t; e < 4096; e += 256) {
      int mm = e >> 6, k = e & 63;
      Vs[mm][k] = g2p[(size_t)(m0 + mm) * DDIM + k];
    }
    softmax_update(Sb, m_b, d_b, 1);
    __syncthreads();
    pv_acc(acc_b, 1);
    __syncthreads();
    // ---- C: restage V=g3 ----
    for (int e = t; e < 4096; e += 256) {
      int mm = e >> 6, k = e & 63;
      Vs[mm][k] = g3p[(size_t)(m0 + mm) * DDIM + k];
    }
    softmax_update(Sc, m_c, d_c, 2);
    __syncthreads();
    pv_acc(acc_c, 2);
  }

  __syncthreads();
  if (lm == 0) { dfin_s[0][lr] = d_a; dfin_s[1][lr] = d_b; dfin_s[2][lr] = d_c; }
  __syncthreads();
#pragma unroll
  for (int i = 0; i < 4; ++i) {
    int r = tr * 4 + i;
    float ia = 1.f / dfin_s[0][r];
    float ib = 1.f / dfin_s[1][r];
    float ic = 1.f / dfin_s[2][r];
    float2 o;
    o.x = acc_a[i][0] * ia + acc_b[i][0] * ib + acc_c[i][0] * ic;
    o.y = acc_a[i][1] * ia + acc_b[i][1] * ib + acc_c[i][1] * ic;
    *(float2*)&fused[(base + l0 + r) * DDIM + tk * 2] = o;
  }
}

// ---------------- z conv: zf[nb][cc][m] = z_w(128x64) @ fused + z_b ----------------
__global__ __launch_bounds__(256) void k_zconv(const float* __restrict__ fused,
                                               const float* __restrict__ zw,
                                               const float* __restrict__ zb,
                                               float* __restrict__ zf) {
  __shared__ __align__(16) float fs[64][68];
  int nb = blockIdx.y;
  int m0 = blockIdx.x * 64;
  int t = threadIdx.x;
  for (int e = t; e < 4096; e += 256) {
    int mm = e >> 6, k = e & 63;
    fs[mm][k] = fused[((size_t)nb * NP + m0 + mm) * DDIM + k];
  }
  __syncthreads();
  int tm = t & 15;   // m' = tm*4 + [0..3]
  int tc = t >> 4;   // cc = tc*8 + [0..7]
  float acc[4][8] = {};
  for (int k = 0; k < DDIM; ++k) {
    float wv[8];
#pragma unroll
    for (int j = 0; j < 8; ++j) wv[j] = zw[(size_t)(tc * 8 + j) * DDIM + k];
    float fv[4];
#pragma unroll
    for (int i = 0; i < 4; ++i) fv[i] = fs[tm * 4 + i][k];
#pragma unroll
    for (int i = 0; i < 4; ++i)
#pragma unroll
      for (int j = 0; j < 8; ++j) acc[i][j] += fv[i] * wv[j];
  }
  for (int j = 0; j < 8; ++j) {
    int cc = tc * 8 + j;
    float b = zb[cc];
    float4 st = { acc[0][j] + b, acc[1][j] + b, acc[2][j] + b, acc[3][j] + b };
    *(float4*)&zf[((size_t)nb * CHN + cc) * NP + m0 + tm * 4] = st;
  }
}

// ---------------- bilinear upsample (align_corners) + residual ----------------
__global__ __launch_bounds__(256) void k_upsample(const float* __restrict__ xin,
                                                  const float* __restrict__ zf,
                                                  float* __restrict__ out) {
  int idx = blockIdx.x * 256 + threadIdx.x;   // NBATCH*CHN*HIMG*WIMG
  int X = idx & 127;
  int Y = (idx >> 7) & 127;
  int pc = idx >> 14;                          // nb*CHN + cc
  const float scale = 63.0f / 127.0f;
  float yf = Y * scale, xf = X * scale;
  int y0 = (int)yf, x0 = (int)xf;
  float wy = yf - y0, wx = xf - x0;
  int y1 = min(y0 + 1, 63), x1 = min(x0 + 1, 63);
  const float* zb_ = zf + (size_t)pc * NP;
  float v00 = zb_[y0 * 64 + x0], v01 = zb_[y0 * 64 + x1];
  float v10 = zb_[y1 * 64 + x0], v11 = zb_[y1 * 64 + x1];
  float r0 = v00 * (1.f - wy) + v10 * wy;
  float r1 = v01 * (1.f - wy) + v11 * wy;
  out[idx] = xin[idx] + (r0 * (1.f - wx) + r1 * wx);
}

extern "C" void kernel_launch(void* const* d_in, const int* in_sizes, int n_in,
                              void* d_out, int out_size, void* d_ws, size_t ws_size,
                              hipStream_t stream) {
  const float* x      = (const float*)d_in[0];
  const float* dmap   = (const float*)d_in[1];
  const float* down_w = (const float*)d_in[2];
  const float* ddw    = (const float*)d_in[3];
  const float* phi_w  = (const float*)d_in[4];
  const float* phi_b  = (const float*)d_in[5];
  const float* fphi_w = (const float*)d_in[6];
  const float* fphi_b = (const float*)d_in[7];
  const float* fth_w  = (const float*)d_in[8];
  const float* fth_b  = (const float*)d_in[9];
  const float* g1_w   = (const float*)d_in[10];
  const float* g1_b   = (const float*)d_in[11];
  const float* g2_w   = (const float*)d_in[12];
  const float* g2_b   = (const float*)d_in[13];
  const float* g3_w   = (const float*)d_in[14];
  const float* g3_b   = (const float*)d_in[15];
  const float* th_w   = (const float*)d_in[16];
  const float* th_b   = (const float*)d_in[17];
  const float* dth_w  = (const float*)d_in[18];
  const float* dth_b  = (const float*)d_in[19];
  const float* dph_w  = (const float*)d_in[20];
  // d_in[21] = d_phi_b cancels in softmax (constant over the softmax axis)
  const float* z_w    = (const float*)d_in[22];
  const float* z_b    = (const float*)d_in[23];
  float* out = (float*)d_out;

  float* ws    = (float*)d_ws;
  float* xf    = ws;                 // 2*128*4096 = 1048576
  float* df    = xf + 1048576;       // 8192
  float* phi   = df + 8192;          // 524288
  float* fphi  = phi + 524288;       // 524288
  float* fth   = fphi + 524288;      // 524288
  float* g1    = fth + 524288;       // 524288
  float* g2    = g1 + 524288;        // 524288
  float* g3    = g2 + 524288;        // 524288
  float* u     = g3 + 524288;        // 8192
  float* v     = u + 8192;           // 8192
  float* fused = v + 8192;           // 524288
  float* zf    = fused + 524288;     // 1048576  (total ~23.2 MB)

  k_down_x<<<4096, 256, 0, stream>>>(x, down_w, xf);
  k_down_d<<<32, 256, 0, stream>>>(dmap, ddw, df);

  dim3 gconv(64, 2);
  k_conv1x1<<<gconv, 256, 0, stream>>>(xf, phi_w,  phi_b,  phi,  0);
  k_conv1x1<<<gconv, 256, 0, stream>>>(xf, fphi_w, fphi_b, fphi, 0);
  k_conv1x1<<<gconv, 256, 0, stream>>>(xf, fth_w,  fth_b,  fth,  1);
  k_conv1x1<<<gconv, 256, 0, stream>>>(xf, g1_w,   g1_b,   g1,   1);
  k_conv1x1<<<gconv, 256, 0, stream>>>(xf, g2_w,   g2_b,   g2,   1);
  k_conv1x1<<<gconv, 256, 0, stream>>>(xf, g3_w,   g3_b,   g3,   1);

  k_uv<<<32, 256, 0, stream>>>(phi, th_w, th_b, u, v);

  dim3 gattn(128, 2);
  k_attn<<<gattn, 256, 0, stream>>>(fphi, fth, g1, g2, g3, df, u, v,
                                    dth_w, dth_b, dph_w, fused);

  k_zconv<<<gconv, 256, 0, stream>>>(fused, z_w, z_b, zf);
  k_upsample<<<16384, 256, 0, stream>>>(x, zf, out);
}

// Round 8
// 303.247 us; speedup vs baseline: 4.3342x; 4.3342x over previous
//
#include <hip/hip_runtime.h>
#include <math.h>

#define NBATCH 2
#define CHN 128
#define HIMG 128
#define WIMG 128
#define DDIM 64
#define NP 4096
#define LOG2E 1.44269504f

typedef float f32x4 __attribute__((ext_vector_type(4)));
typedef short short8 __attribute__((ext_vector_type(8)));

__device__ inline ushort f2bf(float f) {
  uint u = __float_as_uint(f);
  u += 0x7fffu + ((u >> 16) & 1u);
  return (ushort)(u >> 16);
}

__device__ inline float bf2f(ushort u) {
  return __uint_as_float(((uint)u) << 16);
}

// ---------------- downsample x: xf[nb][ch][m] (f32) ----------------
__global__ __launch_bounds__(256) void k_down_x(const float* __restrict__ x,
                                                const float* __restrict__ dw,
                                                float* __restrict__ xf) {
  int idx = blockIdx.x * 256 + threadIdx.x;      // NBATCH*CHN*NP threads
  int m  = idx & (NP - 1);
  int ch = (idx >> 12) & (CHN - 1);
  int nb = idx >> 19;
  int i = m >> 6, j = m & 63;
  const float* xb = x + (((size_t)nb * CHN + ch) * HIMG + 2 * i) * WIMG + 2 * j;
  const float* w = dw + ch * 4;
  xf[idx] = xb[0] * w[0] + xb[1] * w[1] + xb[WIMG] * w[2] + xb[WIMG + 1] * w[3];
}

// ---------------- downsample depth: df[nb][m] ----------------
__global__ __launch_bounds__(256) void k_down_d(const float* __restrict__ dmap,
                                                const float* __restrict__ ddw,
                                                float* __restrict__ df) {
  int idx = blockIdx.x * 256 + threadIdx.x;      // NBATCH*NP threads
  int m = idx & (NP - 1);
  int nb = idx >> 12;
  int i = m >> 6, j = m & 63;
  const float* xb = dmap + ((size_t)nb * HIMG + 2 * i) * WIMG + 2 * j;
  df[idx] = xb[0] * ddw[0] + xb[1] * ddw[1] + xb[WIMG] * ddw[2] + xb[WIMG + 1] * ddw[3];
}

// ---------------- prep: collapse phi-conv into 128-vectors for u,v; scalars ----------------
__global__ void k_prep(const float* __restrict__ thw, const float* __restrict__ thb,
                       const float* __restrict__ phiw, const float* __restrict__ phib,
                       const float* __restrict__ dtw, const float* __restrict__ dtb,
                       const float* __restrict__ dpw,
                       float* __restrict__ wu, float* __restrict__ wv,
                       float* __restrict__ scal) {
  int c = threadIdx.x;  // 128 threads
  float a = 0.f, b = 0.f;
  for (int k = 0; k < DDIM; ++k) {
    float pw = phiw[k * CHN + c];
    a += thw[k] * pw;
    b += thb[k] * pw;
  }
  wu[c] = a; wv[c] = b;
  if (c == 0) {
    float A = 0.f, C = 0.f, bu = 0.f, bv = 0.f;
    for (int k = 0; k < DDIM; ++k) {
      A  += dtw[k] * dpw[k];
      C  += dtb[k] * dpw[k];
      bu += thw[k] * phib[k];
      bv += thb[k] * phib[k];
    }
    scal[0] = A; scal[1] = C; scal[2] = bu; scal[3] = bv;
  }
}

// ---------------- merged 5x 1x1 conv -> bf16 operands ----------------
// z=0: Kb [m][k]   z=1: Qb [l][k] *LOG2E   z=2,3,4: g1/g2/g3 [d][m]
__global__ __launch_bounds__(256) void k_conv5(
    const float* __restrict__ xf,
    const float* W0, const float* B0, ushort* O0,
    const float* W1, const float* B1, ushort* O1,
    const float* W2, const float* B2, ushort* O2,
    const float* W3, const float* B3, ushort* O3,
    const float* W4, const float* B4, ushort* O4) {
  __shared__ __align__(16) float xs[CHN][64];
  int z = blockIdx.z;
  const float* W; const float* B; ushort* O; float scale = 1.f; int mode = 1;
  switch (z) {
    case 0: W = W0; B = B0; O = O0; mode = 0; break;
    case 1: W = W1; B = B1; O = O1; mode = 0; scale = LOG2E; break;
    case 2: W = W2; B = B2; O = O2; break;
    case 3: W = W3; B = B3; O = O3; break;
    default: W = W4; B = B4; O = O4; break;
  }
  int nb = blockIdx.y;
  int m0 = blockIdx.x * 64;
  int t = threadIdx.x;
  const float* xb = xf + (size_t)nb * CHN * NP + m0;
  for (int e = t; e < CHN * 64; e += 256) {
    int c = e >> 6, mm = e & 63;
    xs[c][mm] = xb[(size_t)c * NP + mm];
  }
  __syncthreads();
  int tm = t & 15;   // m' = tm*4 + [0..3]
  int tk = t >> 4;   // k  = tk*4 + [0..3]
  float acc[4][4] = {};
  for (int c = 0; c < CHN; ++c) {
    float w0 = W[(tk * 4 + 0) * CHN + c];
    float w1 = W[(tk * 4 + 1) * CHN + c];
    float w2 = W[(tk * 4 + 2) * CHN + c];
    float w3 = W[(tk * 4 + 3) * CHN + c];
    float4 xv = *(const float4*)&xs[c][tm * 4];
    acc[0][0] += w0 * xv.x; acc[0][1] += w0 * xv.y; acc[0][2] += w0 * xv.z; acc[0][3] += w0 * xv.w;
    acc[1][0] += w1 * xv.x; acc[1][1] += w1 * xv.y; acc[1][2] += w1 * xv.z; acc[1][3] += w1 * xv.w;
    acc[2][0] += w2 * xv.x; acc[2][1] += w2 * xv.y; acc[2][2] += w2 * xv.z; acc[2][3] += w2 * xv.w;
    acc[3][0] += w3 * xv.x; acc[3][1] += w3 * xv.y; acc[3][2] += w3 * xv.z; acc[3][3] += w3 * xv.w;
  }
  float b0 = B[tk * 4 + 0], b1 = B[tk * 4 + 1], b2 = B[tk * 4 + 2], b3 = B[tk * 4 + 3];
  if (mode == 0) {
    // out[(nb*NP + m)*64 + kk], kk = tk*4+i
    for (int j = 0; j < 4; ++j) {
      size_t o = ((size_t)nb * NP + m0 + tm * 4 + j) * DDIM + tk * 4;
      uint w0 = (uint)f2bf((acc[0][j] + b0) * scale) | ((uint)f2bf((acc[1][j] + b1) * scale) << 16);
      uint w1 = (uint)f2bf((acc[2][j] + b2) * scale) | ((uint)f2bf((acc[3][j] + b3) * scale) << 16);
      *(uint*)&O[o] = w0;
      *(uint*)&O[o + 2] = w1;
    }
  } else {
    // out[(nb*64 + d)*NP + m], d = tk*4+i
    float bb[4] = {b0, b1, b2, b3};
    for (int i = 0; i < 4; ++i) {
      size_t o = ((size_t)nb * DDIM + tk * 4 + i) * NP + m0 + tm * 4;
      uint w0 = (uint)f2bf(acc[i][0] + bb[i]) | ((uint)f2bf(acc[i][1] + bb[i]) << 16);
      uint w1 = (uint)f2bf(acc[i][2] + bb[i]) | ((uint)f2bf(acc[i][3] + bb[i]) << 16);
      *(uint*)&O[o] = w0;
      *(uint*)&O[o + 2] = w1;
    }
  }
}

// ---------------- u2,v2 directly from xf (phi never materialized), *LOG2E ----------------
__global__ __launch_bounds__(256) void k_uvd(const float* __restrict__ xf,
                                             const float* __restrict__ wu,
                                             const float* __restrict__ wv,
                                             const float* __restrict__ scal,
                                             float* __restrict__ u2, float* __restrict__ v2) {
  int idx = blockIdx.x * 256 + threadIdx.x;   // NBATCH*NP
  int m = idx & (NP - 1);
  int nb = idx >> 12;
  const float* xb = xf + (size_t)nb * CHN * NP + m;
  float uu = scal[2], vv = scal[3];
  for (int c = 0; c < CHN; ++c) {
    float xv = xb[(size_t)c * NP];
    uu += wu[c] * xv;
    vv += wv[c] * xv;
  }
  u2[idx] = uu * LOG2E;
  v2[idx] = vv * LOG2E;
}

// ---------------- fused triple attention, MFMA, no-max softmax ----------------
// 256 blocks x 512 threads. Block = 2 row-tiles (16 rows each) x 4 column-split waves.
// Denominators are summed from the EXACT bf16 data the PV MFMAs consume, so every
// per-mat output row is a convex combination of V rows by construction (bounded).
__global__ __launch_bounds__(512) void k_attn_mfma(
    const ushort* __restrict__ Qb,   // [nb][l][64] bf16, pre-scaled by LOG2E
    const ushort* __restrict__ Kb,   // [nb][m][64] bf16
    const ushort* __restrict__ g1b,  // [nb][d][m] bf16
    const ushort* __restrict__ g2b,
    const ushort* __restrict__ g3b,
    const float* __restrict__ u2, const float* __restrict__ v2,
    const float* __restrict__ df, const float* __restrict__ scal,
    float* __restrict__ fused) {
  __shared__ __align__(16) ushort Plds[8][16][72];     // wave-private P_c tiles
  __shared__ __align__(16) float accS[2][3][16][64];   // cross-cs merge
  __shared__ float dsumS[2][3][16];

  int tid = threadIdx.x;
  int w = tid >> 6, lane = tid & 63;
  int c = lane & 15, g = lane >> 4;
  int h = w >> 2, cs = w & 3;
  int bid = blockIdx.x;
  int nb = bid & 1, rtp = bid >> 1;       // rtp 0..127
  int l0 = (rtp * 2 + h) * 16;

  // Q fragments (B-operand of swapped QK^T)
  const ushort* qrow = Qb + ((size_t)nb * NP + l0 + c) * DDIM;
  short8 qf0 = *(const short8*)(qrow + g * 8);
  short8 qf1 = *(const short8*)(qrow + 32 + g * 8);

  float df_l = df[nb * NP + l0 + c];
  float sl2 = (scal[0] * df_l + scal[1]) * LOG2E;

  f32x4 acc[3][4];
#pragma unroll
  for (int i = 0; i < 3; ++i)
#pragma unroll
    for (int j = 0; j < 4; ++j) acc[i][j] = (f32x4){0.f, 0.f, 0.f, 0.f};
  float dp0 = 0.f, dp1 = 0.f, dp2 = 0.f;

  const ushort* kbase = Kb + (size_t)nb * NP * DDIM;
  const ushort* g1p = g1b + (size_t)nb * DDIM * NP;
  const ushort* g2p = g2b + (size_t)nb * DDIM * NP;
  const ushort* g3p = g3b + (size_t)nb * DDIM * NP;
  const float* up = u2 + nb * NP;
  const float* vp = v2 + nb * NP;
  const float* dfp = df + nb * NP;

  for (int t = 0; t < 16; ++t) {
    int m0 = t * 256 + cs * 64;

    // ---- S^T = K-tile x Q (swapped): lane holds S(l=c, m=m0+mt*16+g*4+r) ----
    f32x4 sacc[4];
#pragma unroll
    for (int mt = 0; mt < 4; ++mt) {
      const ushort* kr = kbase + (size_t)(m0 + mt * 16 + c) * DDIM;
      short8 ka0 = *(const short8*)(kr + g * 8);
      short8 ka1 = *(const short8*)(kr + 32 + g * 8);
      f32x4 zz = (f32x4){0.f, 0.f, 0.f, 0.f};
      zz = __builtin_amdgcn_mfma_f32_16x16x32_bf16(ka0, qf0, zz, 0, 0, 0);
      zz = __builtin_amdgcn_mfma_f32_16x16x32_bf16(ka1, qf1, zz, 0, 0, 0);
      sacc[mt] = zz;
    }
    // p_c = exp2(S'), pack to bf16 (plain packing, no asm), wave-private LDS
#pragma unroll
    for (int mt = 0; mt < 4; ++mt) {
      uint w0 = (uint)f2bf(exp2f(sacc[mt][0])) | ((uint)f2bf(exp2f(sacc[mt][1])) << 16);
      uint w1 = (uint)f2bf(exp2f(sacc[mt][2])) | ((uint)f2bf(exp2f(sacc[mt][3])) << 16);
      *(uint*)&Plds[w][c][mt * 16 + g * 4]     = w0;
      *(uint*)&Plds[w][c][mt * 16 + g * 4 + 2] = w1;
    }

    // ---- p_a, p_b computed directly in A-frag layout (rank-1 logits) ----
    short8 paf[2], pbf[2];
#pragma unroll
    for (int ks = 0; ks < 2; ++ks) {
      int mb = m0 + ks * 32 + g * 8;
      float pa[8], pb[8];
#pragma unroll
      for (int j = 0; j < 8; ++j) {
        pa[j] = exp2f(df_l * up[mb + j] + vp[mb + j]);
        pb[j] = exp2f(sl2 * dfp[mb + j]);
      }
      short8 a8, b8;
#pragma unroll
      for (int j = 0; j < 8; ++j) {
        ushort ua = f2bf(pa[j]);
        ushort ub = f2bf(pb[j]);
        a8[j] = (short)ua;
        b8[j] = (short)ub;
        dp0 += bf2f(ua);          // denominator from EXACT bf16 MFMA input
        dp1 += bf2f(ub);
      }
      paf[ks] = a8;
      pbf[ks] = b8;
    }

    // p_c fragments back from LDS (wave-private; compiler inserts lgkmcnt)
    short8 pcf0 = *(const short8*)&Plds[w][c][g * 8];
    short8 pcf1 = *(const short8*)&Plds[w][c][32 + g * 8];
#pragma unroll
    for (int j = 0; j < 8; ++j) {   // denominator from the READ-BACK data
      dp2 += bf2f((ushort)pcf0[j]);
      dp2 += bf2f((ushort)pcf1[j]);
    }

    // ---- PV: acc[mat][nt] += P_mat x V_mat ----
#pragma unroll
    for (int nt = 0; nt < 4; ++nt) {
      size_t vro = (size_t)(nt * 16 + c) * NP + m0;
      short8 v10 = *(const short8*)(g1p + vro + g * 8);
      short8 v11 = *(const short8*)(g1p + vro + 32 + g * 8);
      acc[0][nt] = __builtin_amdgcn_mfma_f32_16x16x32_bf16(paf[0], v10, acc[0][nt], 0, 0, 0);
      acc[0][nt] = __builtin_amdgcn_mfma_f32_16x16x32_bf16(paf[1], v11, acc[0][nt], 0, 0, 0);
      short8 v20 = *(const short8*)(g2p + vro + g * 8);
      short8 v21 = *(const short8*)(g2p + vro + 32 + g * 8);
      acc[1][nt] = __builtin_amdgcn_mfma_f32_16x16x32_bf16(pbf[0], v20, acc[1][nt], 0, 0, 0);
      acc[1][nt] = __builtin_amdgcn_mfma_f32_16x16x32_bf16(pbf[1], v21, acc[1][nt], 0, 0, 0);
      short8 v30 = *(const short8*)(g3p + vro + g * 8);
      short8 v31 = *(const short8*)(g3p + vro + 32 + g * 8);
      acc[2][nt] = __builtin_amdgcn_mfma_f32_16x16x32_bf16(pcf0, v30, acc[2][nt], 0, 0, 0);
      acc[2][nt] = __builtin_amdgcn_mfma_f32_16x16x32_bf16(pcf1, v31, acc[2][nt], 0, 0, 0);
    }
  }

  // ---- wave-level row-sum reduce (row = c) ----
  dp0 += __shfl_xor(dp0, 16); dp0 += __shfl_xor(dp0, 32);
  dp1 += __shfl_xor(dp1, 16); dp1 += __shfl_xor(dp1, 32);
  dp2 += __shfl_xor(dp2, 16); dp2 += __shfl_xor(dp2, 32);
  float dpm[3] = {dp0, dp1, dp2};

  // ---- cross-cs merge via LDS, phased ----
  for (int p = 0; p < 4; ++p) {
    __syncthreads();
    if (cs == p) {
#pragma unroll
      for (int mat = 0; mat < 3; ++mat) {
#pragma unroll
        for (int nt = 0; nt < 4; ++nt) {
#pragma unroll
          for (int r = 0; r < 4; ++r) {
            float val = acc[mat][nt][r];
            float* dst = &accS[h][mat][g * 4 + r][nt * 16 + c];
            if (p == 0) *dst = val; else *dst += val;
          }
        }
        if (lane < 16) {
          float* ds = &dsumS[h][mat][c];
          if (p == 0) *ds = dpm[mat]; else *ds += dpm[mat];
        }
      }
    }
  }
  __syncthreads();

  // ---- normalize + write fused[nb][l][d] ----
  {
    int hh = tid >> 8;            // 0..1
    int s = tid & 255;
    int row = s >> 4, d4 = (s & 15) * 4;
    float i0 = 1.f / dsumS[hh][0][row];
    float i1 = 1.f / dsumS[hh][1][row];
    float i2 = 1.f / dsumS[hh][2][row];
    float4 o;
    o.x = accS[hh][0][row][d4 + 0] * i0 + accS[hh][1][row][d4 + 0] * i1 + accS[hh][2][row][d4 + 0] * i2;
    o.y = accS[hh][0][row][d4 + 1] * i0 + accS[hh][1][row][d4 + 1] * i1 + accS[hh][2][row][d4 + 1] * i2;
    o.z = accS[hh][0][row][d4 + 2] * i0 + accS[hh][1][row][d4 + 2] * i1 + accS[hh][2][row][d4 + 2] * i2;
    o.w = accS[hh][0][row][d4 + 3] * i0 + accS[hh][1][row][d4 + 3] * i1 + accS[hh][2][row][d4 + 3] * i2;
    int l = (rtp * 2 + hh) * 16 + row;
    *(float4*)&fused[((size_t)nb * NP + l) * DDIM + d4] = o;
  }
}

// ---------------- z conv: zf[nb][cc][m] = z_w(128x64) @ fused + z_b ----------------
__global__ __launch_bounds__(256) void k_zconv(const float* __restrict__ fused,
                                               const float* __restrict__ zw,
                                               const float* __restrict__ zb,
                                               float* __restrict__ zf) {
  __shared__ __align__(16) float fs[64][68];
  int nb = blockIdx.y;
  int m0 = blockIdx.x * 64;
  int t = threadIdx.x;
  for (int e = t; e < 4096; e += 256) {
    int mm = e >> 6, k = e & 63;
    fs[mm][k] = fused[((size_t)nb * NP + m0 + mm) * DDIM + k];
  }
  __syncthreads();
  int tm = t & 15;
  int tc = t >> 4;
  float acc[4][8] = {};
  for (int k = 0; k < DDIM; ++k) {
    float wv[8];
#pragma unroll
    for (int j = 0; j < 8; ++j) wv[j] = zw[(size_t)(tc * 8 + j) * DDIM + k];
    float fv[4];
#pragma unroll
    for (int i = 0; i < 4; ++i) fv[i] = fs[tm * 4 + i][k];
#pragma unroll
    for (int i = 0; i < 4; ++i)
#pragma unroll
      for (int j = 0; j < 8; ++j) acc[i][j] += fv[i] * wv[j];
  }
  for (int j = 0; j < 8; ++j) {
    int cc = tc * 8 + j;
    float b = zb[cc];
    float4 st = { acc[0][j] + b, acc[1][j] + b, acc[2][j] + b, acc[3][j] + b };
    *(float4*)&zf[((size_t)nb * CHN + cc) * NP + m0 + tm * 4] = st;
  }
}

// ---------------- bilinear upsample (align_corners) + residual ----------------
__global__ __launch_bounds__(256) void k_upsample(const float* __restrict__ xin,
                                                  const float* __restrict__ zf,
                                                  float* __restrict__ out) {
  int idx = blockIdx.x * 256 + threadIdx.x;   // NBATCH*CHN*HIMG*WIMG
  int X = idx & 127;
  int Y = (idx >> 7) & 127;
  int pc = idx >> 14;
  const float scale = 63.0f / 127.0f;
  float yf = Y * scale, xf = X * scale;
  int y0 = (int)yf, x0 = (int)xf;
  float wy = yf - y0, wx = xf - x0;
  int y1 = min(y0 + 1, 63), x1 = min(x0 + 1, 63);
  const float* zb_ = zf + (size_t)pc * NP;
  float v00 = zb_[y0 * 64 + x0], v01 = zb_[y0 * 64 + x1];
  float v10 = zb_[y1 * 64 + x0], v11 = zb_[y1 * 64 + x1];
  float r0 = v00 * (1.f - wy) + v10 * wy;
  float r1 = v01 * (1.f - wy) + v11 * wy;
  out[idx] = xin[idx] + (r0 * (1.f - wx) + r1 * wx);
}

extern "C" void kernel_launch(void* const* d_in, const int* in_sizes, int n_in,
                              void* d_out, int out_size, void* d_ws, size_t ws_size,
                              hipStream_t stream) {
  const float* x      = (const float*)d_in[0];
  const float* dmap   = (const float*)d_in[1];
  const float* down_w = (const float*)d_in[2];
  const float* ddw    = (const float*)d_in[3];
  const float* phi_w  = (const float*)d_in[4];
  const float* phi_b  = (const float*)d_in[5];
  const float* fphi_w = (const float*)d_in[6];
  const float* fphi_b = (const float*)d_in[7];
  const float* fth_w  = (const float*)d_in[8];
  const float* fth_b  = (const float*)d_in[9];
  const float* g1_w   = (const float*)d_in[10];
  const float* g1_b   = (const float*)d_in[11];
  const float* g2_w   = (const float*)d_in[12];
  const float* g2_b   = (const float*)d_in[13];
  const float* g3_w   = (const float*)d_in[14];
  const float* g3_b   = (const float*)d_in[15];
  const float* th_w   = (const float*)d_in[16];
  const float* th_b   = (const float*)d_in[17];
  const float* dth_w  = (const float*)d_in[18];
  const float* dth_b  = (const float*)d_in[19];
  const float* dph_w  = (const float*)d_in[20];
  // d_in[21] = d_phi_b: constant along softmax axis, cancels
  const float* z_w    = (const float*)d_in[22];
  const float* z_b    = (const float*)d_in[23];
  float* out = (float*)d_out;

  float* ws    = (float*)d_ws;
  float* xf    = ws;                  // 1048576
  float* dfb   = xf + 1048576;        // 8192
  float* u2    = dfb + 8192;          // 8192
  float* v2    = u2 + 8192;           // 8192
  float* wu    = v2 + 8192;           // 128
  float* wv    = wu + 128;            // 128
  float* scal  = wv + 128;            // 16
  float* fused = scal + 16;           // 524288
  float* zf    = fused + 524288;      // 1048576
  ushort* Qb   = (ushort*)(zf + 1048576);
  ushort* Kb   = Qb + 524288;
  ushort* g1bb = Kb + 524288;
  ushort* g2bb = g1bb + 524288;
  ushort* g3bb = g2bb + 524288;       // total ~15.8 MB

  k_down_x<<<4096, 256, 0, stream>>>(x, down_w, xf);
  k_down_d<<<32, 256, 0, stream>>>(dmap, ddw, dfb);
  k_prep<<<1, 128, 0, stream>>>(th_w, th_b, phi_w, phi_b, dth_w, dth_b, dph_w, wu, wv, scal);

  dim3 gconv(64, 2, 5);
  k_conv5<<<gconv, 256, 0, stream>>>(xf,
      fphi_w, fphi_b, Kb,
      fth_w,  fth_b,  Qb,
      g1_w, g1_b, g1bb,
      g2_w, g2_b, g2bb,
      g3_w, g3_b, g3bb);

  k_uvd<<<32, 256, 0, stream>>>(xf, wu, wv, scal, u2, v2);

  k_attn_mfma<<<256, 512, 0, stream>>>(Qb, Kb, g1bb, g2bb, g3bb, u2, v2, dfb, scal, fused);

  dim3 gz(64, 2);
  k_zconv<<<gz, 256, 0, stream>>>(fused, z_w, z_b, zf);
  k_upsample<<<16384, 256, 0, stream>>>(x, zf, out);
}